// Round 6
// baseline (413.675 us; speedup 1.0000x reference)
//
#include <hip/hip_runtime.h>
#include <hip/hip_bf16.h>

#define NS 8192
#define NF 45
#define ED 256
#define L1K 11520   // 45*256
#define NH 32
#define CHUNK 2
#define NPH 23      // ceil(45/2)
#define ROWSTRIDE 264           // shorts per staged row (512B data + 16B pad)
#define FSTRIDE (16 * ROWSTRIDE) // shorts per staged feature (4224)

typedef __attribute__((ext_vector_type(8))) short bf16x8;
typedef __attribute__((ext_vector_type(4))) float f32x4;

// PERM / FIELD_OFF precomputed from SECTIONS/FEATURE_SIZES
__constant__ int c_perm[NF] = {
    0,1,2,3,4,5,6,7,8,9,
    10,11,12,13,14,15,16,17,18,19,20,21,22,23,
    26,27, 28,29, 24,25,
    30,31,32,33,34,35,36,37,38,39,40,41,42,43,44};
__constant__ int c_foff[NF] = {
    0,300,1300,2300,2800,2950,2962,2993,2993,2993,
    3023,3023,3023,3023,3023,3023,3023,3023,3023,3023,3023,3023,3023,3023,
    3223,3223, 53223,53223, 103223,103223,
    123223,123223,123223,123223,123223,123223,123223,123223,
    123223,123223,123223,123223,123223,123223,123223};

__device__ __forceinline__ short f2bf(float x) {
    unsigned u = __builtin_bit_cast(unsigned, x);
    u += 0x7fffu + ((u >> 16) & 1u);   // round-to-nearest-even
    return (short)(u >> 16);
}

// packed f32x2 -> bf16x2 (RNE), single instruction on gfx950
__device__ __forceinline__ unsigned pk_bf16(float a, float b) {
    unsigned r;
    asm("v_cvt_pk_bf16_f32 %0, %1, %2" : "=v"(r) : "v"(a), "v"(b));
    return r;
}

__device__ __forceinline__ float bfu_lo(unsigned u) {
    return __builtin_bit_cast(float, (unsigned)(u << 16));
}
__device__ __forceinline__ float bfu_hi(unsigned u) {
    return __builtin_bit_cast(float, (unsigned)(u & 0xffff0000u));
}

// ---------------- kernel 0: pack l1_w into bf16 B-fragment layout --------
// BFRAG[((f*8+ks)*2+nt)*512 + l*8 + i] = bf16( l1w[nt*16+(l&15)][f*256+ks*32+(l>>4)*8+i] )
__global__ __launch_bounds__(256) void k_pack(const float* __restrict__ l1w,
                                              short* __restrict__ bfrag) {
    int t = blockIdx.x * 256 + threadIdx.x;
    if (t >= NF * 8192) return;
    int i  = t & 7;
    int l  = (t >> 3) & 63;
    int nt = (t >> 9) & 1;
    int ks = (t >> 10) & 7;
    int f  = t >> 13;
    int kout = nt * 16 + (l & 15);
    int col  = f * 256 + ks * 32 + (l >> 4) * 8 + i;
    bfrag[t] = f2bf(l1w[kout * L1K + col]);
}

// ---------------- kernel 1: row-cooperative gather + FM + deep GEMM ------
// 512 blocks x 256 thr (4 waves). Block owns 16 samples, full 256 dims.
// Staging: each W2 row (1 KB) is loaded by one wave in ONE coalesced
// dwordx4 (64 lanes x 16 B), scaled by xv, packed bf16, stored to LDS
// row-major (528 B stride). Consumers ds_read_b128 MFMA A-fragments.
// Double-buffered 2-feature chunks; wave w covers MFMA k-steps 2w, 2w+1.
__global__ __launch_bounds__(256) void k_main(const float* __restrict__ W2,
                                              const float* __restrict__ W1,
                                              const int* __restrict__ Xi,
                                              const float* __restrict__ Xv,
                                              const short* __restrict__ bfrag,
                                              float* __restrict__ h1pre,
                                              float* __restrict__ partial) {
    __shared__ int   s_idx[16 * NF];
    __shared__ float s_xv [16 * NF];
    __shared__ short s_e[2][CHUNK * FSTRIDE];   // 2 x 16.5 KB staged e (bf16)
    __shared__ float s_red[4 * 512];            // 8 KB wave partials of h1pre
    __shared__ float s_q[4][16];
    __shared__ float s_fm1[16];

    const int tid = threadIdx.x;
    const int w   = tid >> 6;      // wave 0..3
    const int l   = tid & 63;
    const int m   = l & 15;        // MFMA A-row (sample) for consumption
    const int g4  = l >> 4;        // k-quad within fragment
    const int n0  = blockIdx.x * 16;

    if (tid < 16) s_fm1[tid] = 0.f;
    for (int t = tid; t < 16 * NF; t += 256) {
        int f = t % NF;
        int n = n0 + t / NF;
        int col = c_perm[f];
        s_idx[t] = Xi[n * NF + col] + c_foff[f];
        s_xv[t]  = Xv[n * NF + col];
    }
    __syncthreads();

    f32x4 acc0 = {0.f, 0.f, 0.f, 0.f};
    f32x4 acc1 = {0.f, 0.f, 0.f, 0.f};
    float sA[16];
    #pragma unroll
    for (int i = 0; i < 16; ++i) sA[i] = 0.f;
    float esq = 0.f;

    // ---------- stage phase 0 into buf 0 ----------
    {
        const int nrows = 16 * CHUNK;   // phase 0 is full
        #pragma unroll
        for (int j = 0; j < 8; ++j) {
            int rr = w * 8 + j;         // 0..31
            int fi = rr >> 4;
            int mm = rr & 15;
            int f  = fi;                // phase 0: f = fi
            int idx  = s_idx[mm * NF + f];
            float xv = s_xv [mm * NF + f];
            f32x4 a = *(const f32x4*)(W2 + (size_t)idx * ED + l * 4);
            if (l == 0) atomicAdd(&s_fm1[mm], W1[idx] * xv);
            uint2 v;
            v.x = pk_bf16(a.x * xv, a.y * xv);
            v.y = pk_bf16(a.z * xv, a.w * xv);
            *(uint2*)(&s_e[0][fi * FSTRIDE + mm * ROWSTRIDE + l * 4]) = v;
            (void)nrows;
        }
    }
    __syncthreads();

    for (int p = 0; p < NPH; ++p) {
        const int cur = p & 1;

        // ---------- stage phase p+1 into the other buffer ----------
        if (p + 1 < NPH) {
            const int pn = p + 1;
            const int nf = (pn * CHUNK + CHUNK <= NF) ? CHUNK : (NF - pn * CHUNK);
            const int nrows = nf * 16;
            #pragma unroll
            for (int j = 0; j < 8; ++j) {
                int rr = w * 8 + j;
                if (rr < nrows) {
                    int fi = rr >> 4;
                    int mm = rr & 15;
                    int f  = pn * CHUNK + fi;
                    int idx  = s_idx[mm * NF + f];
                    float xv = s_xv [mm * NF + f];
                    f32x4 a = *(const f32x4*)(W2 + (size_t)idx * ED + l * 4);
                    if (l == 0) atomicAdd(&s_fm1[mm], W1[idx] * xv);
                    uint2 v;
                    v.x = pk_bf16(a.x * xv, a.y * xv);
                    v.y = pk_bf16(a.z * xv, a.w * xv);
                    *(uint2*)(&s_e[cur ^ 1][fi * FSTRIDE + mm * ROWSTRIDE + l * 4]) = v;
                }
            }
        }

        // ---------- consume phase p from buffer cur ----------
        {
            const int nf = (p * CHUNK + CHUNK <= NF) ? CHUNK : (NF - p * CHUNK);
            #pragma unroll
            for (int fi = 0; fi < CHUNK; ++fi) {
                if (fi < nf) {
                    const int f = p * CHUNK + fi;
                    #pragma unroll
                    for (int kk = 0; kk < 2; ++kk) {
                        const int ks = w * 2 + kk;
                        bf16x8 af = *(const bf16x8*)
                            (&s_e[cur][fi * FSTRIDE + m * ROWSTRIDE + ks * 32 + g4 * 8]);
                        const short* bp = bfrag + (size_t)f * 8192 + ks * 1024 + l * 8;
                        bf16x8 b0 = *(const bf16x8*)(bp);
                        bf16x8 b1 = *(const bf16x8*)(bp + 512);

                        union { bf16x8 v; unsigned u[4]; } A;
                        A.v = af;
                        #pragma unroll
                        for (int d = 0; d < 4; ++d) {
                            float elo = bfu_lo(A.u[d]);
                            float ehi = bfu_hi(A.u[d]);
                            sA[kk * 8 + 2 * d]     += elo;
                            sA[kk * 8 + 2 * d + 1] += ehi;
                            esq += elo * elo + ehi * ehi;
                        }
                        acc0 = __builtin_amdgcn_mfma_f32_16x16x32_bf16(af, b0, acc0, 0, 0, 0);
                        acc1 = __builtin_amdgcn_mfma_f32_16x16x32_bf16(af, b1, acc1, 0, 0, 0);
                    }
                }
            }
        }
        __syncthreads();
    }

    // fm2 partial over this wave's 64 dims: sum(sA^2) - sum(e^2)
    float q = -esq;
    #pragma unroll
    for (int i = 0; i < 16; ++i) q += sA[i] * sA[i];
    q += __shfl_xor(q, 16);
    q += __shfl_xor(q, 32);
    if (l < 16) s_q[w][l] = q;

    // stash wave-partial h1pre (D layout: sample=(l>>4)*4+r, j=l&15 [+16 for acc1])
    #pragma unroll
    for (int r = 0; r < 4; ++r) {
        s_red[w * 512 + (g4 * 4 + r) * 32 +      m] = acc0[r];
        s_red[w * 512 + (g4 * 4 + r) * 32 + 16 + m] = acc1[r];
    }
    __syncthreads();

    for (int t = tid; t < 512; t += 256) {
        float v = s_red[t] + s_red[512 + t] + s_red[1024 + t] + s_red[1536 + t];
        h1pre[(size_t)n0 * NH + t] = v;   // t = s*32 + k, contiguous
    }
    if (tid < 16) {
        float fm2 = 0.5f * (s_q[0][tid] + s_q[1][tid] + s_q[2][tid] + s_q[3][tid]);
        partial[n0 + tid] = s_fm1[tid] + fm2;
    }
}

// ---------------- kernel 2: S1[32], S2[32][32] over the batch ------------
__global__ __launch_bounds__(256) void k_stats(const float* __restrict__ h1pre,
                                               float* __restrict__ S1,
                                               float* __restrict__ S2) {
    __shared__ float hc[128 * NH];   // 16 KB
    const int tid = threadIdx.x;
    const int base = blockIdx.x * 128;   // 64 blocks
    for (int t = tid; t < 128 * NH; t += 256) hc[t] = h1pre[(size_t)base * NH + t];
    __syncthreads();

    const int j = tid >> 3;
    const int ks = (tid & 7) * 4;
    float a0 = 0.f, a1 = 0.f, a2 = 0.f, a3 = 0.f;
    for (int n = 0; n < 128; ++n) {
        float hj = hc[n * NH + j];
        f32x4 h = *(const f32x4*)&hc[n * NH + ks];
        a0 += hj * h.x; a1 += hj * h.y; a2 += hj * h.z; a3 += hj * h.w;
    }
    atomicAdd(&S2[j * NH + ks + 0], a0);
    atomicAdd(&S2[j * NH + ks + 1], a1);
    atomicAdd(&S2[j * NH + ks + 2], a2);
    atomicAdd(&S2[j * NH + ks + 3], a3);
    if (tid < NH) {
        float s = 0.f;
        for (int n = 0; n < 128; ++n) s += hc[n * NH + tid];
        atomicAdd(&S1[tid], s);
    }
}

// ---------------- kernel 3: analytic BN folding -> c[32], K0 -------------
__global__ __launch_bounds__(256) void k_coef(const float* __restrict__ S1,
                                              const float* __restrict__ S2,
                                              const float* __restrict__ g1,
                                              const float* __restrict__ l2w,
                                              const float* __restrict__ g2,
                                              const float* __restrict__ b2,
                                              const float* __restrict__ bias,
                                              float* __restrict__ cvec,
                                              float* __restrict__ k0out) {
    __shared__ float m1[NH], d1[NH], g2r2[NH], csh[NH];
    const int t = threadIdx.x;
    const float invN = 1.f / (float)NS;
    if (t < NH) {
        float mm = S1[t] * invN;
        float v1 = S2[t * NH + t] * invN - mm * mm;
        m1[t] = mm;
        d1[t] = g1[t] * rsqrtf(v1 + 1e-5f);
    }
    __syncthreads();
    if (t < NH) {
        float aw[NH];
        float p = 0.f;
        for (int j = 0; j < NH; ++j) { aw[j] = l2w[t * NH + j] * d1[j]; p += aw[j] * m1[j]; }
        float v2 = 0.f;
        for (int j = 0; j < NH; ++j) {
            float acc = 0.f;
            for (int j2 = 0; j2 < NH; ++j2) acc += aw[j2] * S2[j * NH + j2];
            v2 += aw[j] * acc;
        }
        v2 = v2 * invN - p * p;
        g2r2[t] = g2[t] * rsqrtf(v2 + 1e-5f);
    }
    __syncthreads();
    if (t < NH) {
        float s = 0.f;
        for (int k = 0; k < NH; ++k) s += g2r2[k] * l2w[k * NH + t];
        float c = d1[t] * s;
        csh[t] = c;
        cvec[t] = c;
    }
    __syncthreads();
    if (t == 0) {
        float k0 = bias[0];
        for (int k = 0; k < NH; ++k) k0 += b2[k];
        for (int j = 0; j < NH; ++j) k0 -= csh[j] * m1[j];
        k0out[0] = k0;
    }
}

// ---------------- kernel 4: finalize -------------------------------------
__global__ __launch_bounds__(256) void k_final(const float* __restrict__ h1pre,
                                               const float* __restrict__ partial,
                                               const float* __restrict__ cvec,
                                               const float* __restrict__ k0p,
                                               float* __restrict__ out) {
    __shared__ float c[NH];
    __shared__ float k0s;
    const int t = threadIdx.x;
    if (t < NH) c[t] = cvec[t];
    if (t == 0) k0s = k0p[0];
    __syncthreads();
    const int n = blockIdx.x * 256 + t;
    const f32x4* hp = (const f32x4*)(h1pre + (size_t)n * NH);
    float dot = 0.f;
    #pragma unroll
    for (int q = 0; q < 8; ++q) {
        f32x4 h = hp[q];
        dot += h.x * c[q * 4] + h.y * c[q * 4 + 1] + h.z * c[q * 4 + 2] + h.w * c[q * 4 + 3];
    }
    out[n] = partial[n] + dot + k0s;
}

extern "C" void kernel_launch(void* const* d_in, const int* in_sizes, int n_in,
                              void* d_out, int out_size, void* d_ws, size_t ws_size,
                              hipStream_t stream) {
    const int*   Xi   = (const int*)  d_in[0];
    const float* Xv   = (const float*)d_in[1];
    const float* W1   = (const float*)d_in[2];
    const float* W2   = (const float*)d_in[3];
    const float* bias = (const float*)d_in[4];
    const float* l1w  = (const float*)d_in[5];
    // d_in[6] = l1_b  (cancels under BN)
    const float* g1   = (const float*)d_in[7];
    // d_in[8] = bn1_b (cancels)
    const float* l2w  = (const float*)d_in[9];
    // d_in[10] = l2_b (cancels)
    const float* g2   = (const float*)d_in[11];
    const float* b2   = (const float*)d_in[12];
    float* out = (float*)d_out;

    char* ws = (char*)d_ws;
    short* bfrag = (short*)ws;                          // 368640 bf16
    float* h1    = (float*)(ws + (size_t)368640 * 2);   // 8192*32 f
    float* part  = h1 + (size_t)NS * NH;                // 8192 f
    float* S1    = part + NS;                           // 32
    float* S2    = S1 + NH;                             // 1024
    float* cvec  = S2 + NH * NH;                        // 32
    float* k0p   = cvec + NH;                           // 1

    hipMemsetAsync(S1, 0, (NH + NH * NH) * sizeof(float), stream);
    k_pack <<<(NF * 8192 + 255) / 256, 256, 0, stream>>>(l1w, bfrag);
    k_main <<<NS / 16, 256, 0, stream>>>(W2, W1, Xi, Xv, bfrag, h1, part);
    k_stats<<<64, 256, 0, stream>>>(h1, S1, S2);
    k_coef <<<1, 256, 0, stream>>>(S1, S2, g1, l2w, g2, b2, bias, cvec, k0p);
    k_final<<<NS / 256, 256, 0, stream>>>(h1, part, cvec, k0p, out);
}